// Round 4
// baseline (317.704 us; speedup 1.0000x reference)
//
#include <hip/hip_runtime.h>
#include <math.h>

// Problem constants
#define B_    32
#define C3_   1024
#define C4_   2048
#define C_    3072
#define P_    784      // 28*28
#define Q_    196      // 14*14
#define L_    9
#define NG_   25088    // B_*P_
#define A_    312
#define NC_   200

// d_out layout (floats): attr(32x312), class(32x200), maps(32x9x784), af(32x3072x9)
#define ATTR_OFF  0
#define CLASS_OFF 9984
#define MAPS_OFF  16384
#define AF_OFF    242176

// workspace layout (floats)
#define ASQ_OFF   0
#define MF_OFF    16
#define PART3_OFF 98320                          // 16 slabs x 9 x NG_ = 3612672
#define PAF_OFF   98320                          // alias: l3 af partials 4x32x1024x9
                                                 // (part3 dead after kC; paf written in kE)
#define Y4P_OFF   (PART3_OFF + 16 * 9 * NG_)     // 3710992 ; 32 x 32 x 9 x 196
#define Y_OFF     (Y4P_OFF + 32 * 32 * 9 * Q_)   // 5517328 ; 32 x 9 x 196
#define MP_OFF    (Y_OFF + 32 * 9 * Q_)          // 5573776 ; 32 x 9 x 196
// end: 5630224 floats = 22.5 MB

typedef __attribute__((ext_vector_type(8))) short bf16x8;
typedef __attribute__((ext_vector_type(4))) float f32x4;

__device__ __forceinline__ short f2bf(float f) {
    union { float f; unsigned u; } v; v.f = f;
    unsigned r = v.u + 0x7FFFu + ((v.u >> 16) & 1u);   // RNE
    return (short)(r >> 16);
}

// ============================================================= K_A (fused)
// blocks [0,392): l3 ab-partials. thread = (slab of 64ch, b, 4-px chunk), float4 loads
// blocks [392,588): l4 contraction at 14x14. thread = (grp of 64ch, b, 4-q chunk)
// block 588: a_sq
__global__ __launch_bounds__(256) void kA(
        const float* __restrict__ l3, const float* __restrict__ l4,
        const float* __restrict__ conv_w,
        float* __restrict__ part3, float* __restrict__ y4p,
        float* __restrict__ asq) {
    int bid = blockIdx.x;
    int t = threadIdx.x;
    if (bid < 392) {
        int tid = bid * 256 + t;               // [0, 100352)
        int slab = tid / 6272;                 // 16 slabs of 64 ch
        int rem = tid % 6272;
        int b = rem / 196, chunk = rem % 196;
        int px = chunk * 4;
        int c0 = slab * 64;                    // l3-local channel base
        const float* xp = l3 + ((size_t)b * C3_ + c0) * P_ + px;
        float ab[9][4];
#pragma unroll
        for (int l = 0; l < 9; ++l)
#pragma unroll
            for (int j = 0; j < 4; ++j) ab[l][j] = 0.f;
        for (int c = 0; c < 64; c += 8) {
            float4 v[8];
#pragma unroll
            for (int k = 0; k < 8; ++k)
                v[k] = *(const float4*)(xp + (size_t)(c + k) * P_);
#pragma unroll
            for (int l = 0; l < 9; ++l) {
                const float4 w0 = *(const float4*)(conv_w + l * C_ + C4_ + c0 + c);
                const float4 w1 = *(const float4*)(conv_w + l * C_ + C4_ + c0 + c + 4);
                const float wv[8] = {w0.x, w0.y, w0.z, w0.w, w1.x, w1.y, w1.z, w1.w};
#pragma unroll
                for (int k = 0; k < 8; ++k) {
                    ab[l][0] = fmaf(wv[k], v[k].x, ab[l][0]);
                    ab[l][1] = fmaf(wv[k], v[k].y, ab[l][1]);
                    ab[l][2] = fmaf(wv[k], v[k].z, ab[l][2]);
                    ab[l][3] = fmaf(wv[k], v[k].w, ab[l][3]);
                }
            }
        }
#pragma unroll
        for (int l = 0; l < 9; ++l)
            *(float4*)(part3 + (size_t)(slab * 9 + l) * NG_ + b * P_ + px) =
                make_float4(ab[l][0], ab[l][1], ab[l][2], ab[l][3]);
    } else if (bid < 588) {
        int tid = (bid - 392) * 256 + t;       // [0, 50176)
        int grp = tid / 1568;                  // 32 grps of 64 ch
        int rem = tid % 1568;
        int b = rem / 49, chunk = rem % 49;
        int q = chunk * 4;
        int c0 = grp * 64;
        const float* xp = l4 + ((size_t)b * C4_ + c0) * Q_ + q;
        float ac[9][4];
#pragma unroll
        for (int l = 0; l < 9; ++l)
#pragma unroll
            for (int j = 0; j < 4; ++j) ac[l][j] = 0.f;
        for (int c = 0; c < 64; c += 8) {
            float4 v[8];
#pragma unroll
            for (int k = 0; k < 8; ++k)
                v[k] = *(const float4*)(xp + (size_t)(c + k) * Q_);
#pragma unroll
            for (int l = 0; l < 9; ++l) {
                const float4 w0 = *(const float4*)(conv_w + l * C_ + c0 + c);
                const float4 w1 = *(const float4*)(conv_w + l * C_ + c0 + c + 4);
                const float wv[8] = {w0.x, w0.y, w0.z, w0.w, w1.x, w1.y, w1.z, w1.w};
#pragma unroll
                for (int k = 0; k < 8; ++k) {
                    ac[l][0] = fmaf(wv[k], v[k].x, ac[l][0]);
                    ac[l][1] = fmaf(wv[k], v[k].y, ac[l][1]);
                    ac[l][2] = fmaf(wv[k], v[k].z, ac[l][2]);
                    ac[l][3] = fmaf(wv[k], v[k].w, ac[l][3]);
                }
            }
        }
#pragma unroll
        for (int l = 0; l < 9; ++l)
            *(float4*)(y4p + (size_t)((b * 32 + grp) * 9 + l) * Q_ + q) =
                make_float4(ac[l][0], ac[l][1], ac[l][2], ac[l][3]);
    } else {
        __shared__ float red[256];
        for (int l = 0; l < L_; ++l) {
            float s = 0.f;
            for (int c = t; c < C_; c += 256) s += conv_w[l * C_ + c];
            red[t] = s; __syncthreads();
            for (int o = 128; o > 0; o >>= 1) {
                if (t < o) red[t] += red[t + o];
                __syncthreads();
            }
            if (t == 0) asq[l] = red[0];
            __syncthreads();
        }
    }
}

// ================================================= K_B: reduce y4p -> Y[b,l,q]
__global__ __launch_bounds__(256) void kB(const float* __restrict__ y4p,
                                          float* __restrict__ Y) {
    int tid = blockIdx.x * 256 + threadIdx.x;
    if (tid >= 32 * 9 * Q_) return;
    int b = tid / (9 * Q_);
    int r = tid % (9 * Q_);
    float s = 0.f;
#pragma unroll
    for (int grp = 0; grp < 32; ++grp)
        s += y4p[(size_t)(b * 32 + grp) * (9 * Q_) + r];
    Y[(size_t)b * (9 * Q_) + r] = s;
}

// =================== K_C: assemble ab (upsample Y + l3 partials) + softmax
__global__ __launch_bounds__(256) void kC(const float* __restrict__ part3,
                                          const float* __restrict__ Y,
                                          const float* __restrict__ asq,
                                          float* __restrict__ out_maps) {
    int g = blockIdx.x * 256 + threadIdx.x;   // 0..25087
    int b = g / P_, p = g % P_;
    int yy = p / 28, xx = p % 28;
    float sy = 0.5f * yy - 0.25f, sx = 0.5f * xx - 0.25f;
    float fyf = floorf(sy), fxf = floorf(sx);
    float fy = sy - fyf, fx = sx - fxf;
    int ya = max(0, (int)fyf), yb = min(13, (int)fyf + 1);
    int xa = max(0, (int)fxf), xb = min(13, (int)fxf + 1);
    int o00 = ya * 14 + xa, o01 = ya * 14 + xb;
    int o10 = yb * 14 + xa, o11 = yb * 14 + xb;
    float w00 = (1.f - fy) * (1.f - fx), w01 = (1.f - fy) * fx;
    float w10 = fy * (1.f - fx),         w11 = fy * fx;
    const float* Yb = Y + (size_t)b * (9 * Q_);
    float v[9];
#pragma unroll
    for (int l = 0; l < 9; ++l) {
        const float* Yl = Yb + l * Q_;
        float ab4 = w00 * Yl[o00] + w01 * Yl[o01] + w10 * Yl[o10] + w11 * Yl[o11];
        float ab3 = 0.f;
#pragma unroll
        for (int sl = 0; sl < 16; ++sl)
            ab3 += part3[(size_t)(sl * 9 + l) * NG_ + g];
        v[l] = 2.f * (ab4 + ab3) - asq[l];    // b_sq cancels in softmax over l
    }
    float m = v[0];
#pragma unroll
    for (int l = 1; l < 9; ++l) m = fmaxf(m, v[l]);
    float sum = 0.f;
#pragma unroll
    for (int l = 0; l < 9; ++l) { v[l] = expf(v[l] - m); sum += v[l]; }
    float inv = 1.f / sum;
#pragma unroll
    for (int l = 0; l < 9; ++l)
        out_maps[(size_t)b * (L_ * P_) + l * P_ + p] = v[l] * inv;
}

// ============== K_D: adjoint bilinear downsample of maps -> Mp[b,l,q]
__device__ __forceinline__ int adj_taps(int q, int* ys, float* wy) {
    if (q == 0)  { ys[0] = 0;  wy[0] = 1.00f; ys[1] = 1;  wy[1] = 0.75f;
                   ys[2] = 2;  wy[2] = 0.25f; return 3; }
    if (q == 13) { ys[0] = 25; wy[0] = 0.25f; ys[1] = 26; wy[1] = 0.75f;
                   ys[2] = 27; wy[2] = 1.00f; return 3; }
    ys[0] = 2 * q - 1; wy[0] = 0.25f;
    ys[1] = 2 * q;     wy[1] = 0.75f;
    ys[2] = 2 * q + 1; wy[2] = 0.75f;
    ys[3] = 2 * q + 2; wy[3] = 0.25f;
    return 4;
}

__global__ __launch_bounds__(256) void kD(const float* __restrict__ maps,
                                          float* __restrict__ Mp) {
    int tid = blockIdx.x * 256 + threadIdx.x;
    if (tid >= 32 * 9 * Q_) return;
    int b = tid / (9 * Q_);
    int r = tid % (9 * Q_);
    int l = r / Q_, q = r % Q_;
    int qy = q / 14, qx = q % 14;
    int ys[4], xs[4]; float wy[4], wx[4];
    int ny = adj_taps(qy, ys, wy);
    int nx = adj_taps(qx, xs, wx);
    const float* mrow = maps + (size_t)b * (L_ * P_) + l * P_;
    float s = 0.f;
    for (int i = 0; i < ny; ++i) {
        float rs = 0.f;
        for (int j = 0; j < nx; ++j)
            rs = fmaf(wx[j], mrow[ys[i] * 28 + xs[j]], rs);
        s = fmaf(wy[i], rs, s);
    }
    Mp[(size_t)b * (9 * Q_) + r] = s;
}

// ===================== K_E: all_features via LDS-staged MFMA bf16
// tile: 64 channels x 196 pixels; 4 waves, wave w owns channels [w*16, w*16+16)
// blocks [0,1024): l4 (b, 32 grps of 64) K=196 vs Mp -> writes out_af FINAL
// blocks [1024,3072): l3 (b, 16 grps of 64, 4 K-chunks of 196) -> partials in paf
#define SA 232     // LDS row stride (bf16 elems): 196 data + pad to 224 + bank skew
__global__ __launch_bounds__(256) void kE(
        const float* __restrict__ l3, const float* __restrict__ l4,
        const float* __restrict__ maps, const float* __restrict__ Mp,
        float* __restrict__ out_af, float* __restrict__ paf) {
    __shared__ short As[64 * SA];   // 29696 B
    __shared__ short Bs[16 * SA];   //  7424 B
    int bid = blockIdx.x;
    int t = threadIdx.x;
    int wave = t >> 6, lane = t & 63;
    int row16 = lane & 15, quad = lane >> 4;

    const float* xsrc; size_t xstride;
    const float* bsrc; size_t bstride;
    int b, c0, h;
    bool isl4 = (bid < 1024);
    if (isl4) {
        b = bid >> 5;
        c0 = (bid & 31) * 64;
        h = 0;
        xsrc = l4 + ((size_t)b * C4_ + c0) * Q_;
        xstride = Q_;
        bsrc = Mp + (size_t)b * (9 * Q_);
        bstride = Q_;
    } else {
        int idx = bid - 1024;
        b = idx >> 6;
        c0 = ((idx >> 2) & 15) * 64;
        h = idx & 3;
        xsrc = l3 + ((size_t)b * C3_ + c0) * P_ + h * Q_;
        xstride = P_;
        bsrc = maps + (size_t)b * (L_ * P_) + h * Q_;
        bstride = P_;
    }

    // stage A: 64 rows x 49 float4 -> bf16
    for (int i = t; i < 64 * 49; i += 256) {
        int r = i / 49, j = (i % 49) * 4;
        float4 v = *(const float4*)(xsrc + (size_t)r * xstride + j);
        ushort4 o;
        o.x = (unsigned short)f2bf(v.x); o.y = (unsigned short)f2bf(v.y);
        o.z = (unsigned short)f2bf(v.z); o.w = (unsigned short)f2bf(v.w);
        *(ushort4*)(As + r * SA + j) = o;
    }
    // zero-pad A cols [196,232)
    for (int i = t; i < 64 * 9; i += 256) {
        int r = i / 9, j = 196 + (i % 9) * 4;
        *(ushort4*)(As + r * SA + j) = make_ushort4(0, 0, 0, 0);
    }
    // stage B: 16 rows x 58 groups (rows>=9 and cols>=196 zero)
    for (int i = t; i < 16 * 58; i += 256) {
        int r = i / 58, j = (i % 58) * 4;
        ushort4 o = make_ushort4(0, 0, 0, 0);
        if (r < 9 && j < 196) {
            float4 v = *(const float4*)(bsrc + (size_t)r * bstride + j);
            o.x = (unsigned short)f2bf(v.x); o.y = (unsigned short)f2bf(v.y);
            o.z = (unsigned short)f2bf(v.z); o.w = (unsigned short)f2bf(v.w);
        }
        *(ushort4*)(Bs + r * SA + j) = o;
    }
    __syncthreads();

    const short* arow = As + (wave * 16 + row16) * SA;
    const short* brow = Bs + row16 * SA;
    f32x4 acc = {0.f, 0.f, 0.f, 0.f};
#pragma unroll
    for (int k0 = 0; k0 < 224; k0 += 32) {
        bf16x8 a = *(const bf16x8*)(arow + k0 + quad * 8);
        bf16x8 bv = *(const bf16x8*)(brow + k0 + quad * 8);
        acc = __builtin_amdgcn_mfma_f32_16x16x32_bf16(a, bv, acc, 0, 0, 0);
    }
    // D layout: col = lane&15 (= landmark l), row = quad*4 + reg (= channel)
    int l = row16;
    if (l < 9) {
        int c = c0 + wave * 16 + quad * 4;     // first of 4 channels
        if (isl4) {
            size_t base = ((size_t)b * C_ + c) * 9 + l;
#pragma unroll
            for (int r = 0; r < 4; ++r)
                out_af[base + (size_t)r * 9] = acc[r] * (1.f / 784.f);
        } else {
            size_t base = ((size_t)(h * B_ + b) * C3_ + c) * 9 + l;
#pragma unroll
            for (int r = 0; r < 4; ++r)
                paf[base + (size_t)r * 9] = acc[r];
        }
    }
}

// ============ K_MF: combine l3 partials -> af, and mean_features for all c
__global__ __launch_bounds__(256) void kMF(const float* __restrict__ paf,
                                           const float* __restrict__ mod,
                                           float* __restrict__ out_af,
                                           float* __restrict__ mf) {
    int i = blockIdx.x * 256 + threadIdx.x;   // b*C + c
    if (i >= B_ * C_) return;
    int b = i / C_, c = i % C_;
    float af[9];
    if (c < C4_) {
#pragma unroll
        for (int l = 0; l < 9; ++l) af[l] = out_af[(size_t)i * 9 + l];
    } else {
        int c3 = c - C4_;
#pragma unroll
        for (int l = 0; l < 9; ++l) {
            float s = 0.f;
#pragma unroll
            for (int hh = 0; hh < 4; ++hh)
                s += paf[((size_t)(hh * B_ + b) * C3_ + c3) * 9 + l];
            af[l] = s * (1.f / 784.f);
            out_af[(size_t)i * 9 + l] = af[l];
        }
    }
    const float* m = mod + (size_t)c * 9;
    float s = 0.f;
#pragma unroll
    for (int l = 0; l < 8; ++l) s = fmaf(af[l], m[l], s);
    mf[i] = s * 0.125f;
}

// -------------------------------------------------- K_F: attr = mf @ attr_w.T
__global__ __launch_bounds__(256) void kF(
        const float* __restrict__ mf, const float* __restrict__ attr_w,
        const float* __restrict__ attr_b, float* __restrict__ out_attr) {
    int idx = blockIdx.x * 4 + (threadIdx.x >> 6);   // idx = b*312 + a
    int lane = threadIdx.x & 63;
    int b = idx / A_, a = idx % A_;
    const float4* wr = (const float4*)(attr_w + (size_t)a * C_);
    const float4* mr = (const float4*)(mf + (size_t)b * C_);
    float acc = 0.f;
    for (int j = lane; j < C_ / 4; j += 64) {
        float4 w = wr[j], m = mr[j];
        acc += w.x * m.x + w.y * m.y + w.z * m.z + w.w * m.w;
    }
    acc += __shfl_xor(acc, 1);  acc += __shfl_xor(acc, 2);
    acc += __shfl_xor(acc, 4);  acc += __shfl_xor(acc, 8);
    acc += __shfl_xor(acc, 16); acc += __shfl_xor(acc, 32);
    if (lane == 0) out_attr[idx] = acc + attr_b[a];
}

// ---------------------------------------------- K_G: class = attr @ class_w.T
__global__ __launch_bounds__(256) void kG(
        const float* __restrict__ attr, const float* __restrict__ class_w,
        float* __restrict__ out_class) {
    int idx = blockIdx.x * 4 + (threadIdx.x >> 6);   // idx = b*200 + n
    int lane = threadIdx.x & 63;
    int b = idx / NC_, n = idx % NC_;
    float acc = 0.f;
    for (int a = lane; a < A_; a += 64)
        acc += attr[b * A_ + a] * class_w[n * A_ + a];
    acc += __shfl_xor(acc, 1);  acc += __shfl_xor(acc, 2);
    acc += __shfl_xor(acc, 4);  acc += __shfl_xor(acc, 8);
    acc += __shfl_xor(acc, 16); acc += __shfl_xor(acc, 32);
    if (lane == 0) out_class[idx] = acc;
}

extern "C" void kernel_launch(void* const* d_in, const int* in_sizes, int n_in,
                              void* d_out, int out_size, void* d_ws, size_t ws_size,
                              hipStream_t stream) {
    (void)in_sizes; (void)n_in; (void)out_size; (void)ws_size;
    const float* l3         = (const float*)d_in[0];
    const float* l4         = (const float*)d_in[1];
    const float* conv_w     = (const float*)d_in[2];
    const float* modulation = (const float*)d_in[3];
    const float* attr_w     = (const float*)d_in[4];
    const float* attr_b     = (const float*)d_in[5];
    const float* class_w    = (const float*)d_in[6];
    float* out = (float*)d_out;
    float* ws  = (float*)d_ws;
    float* asq   = ws + ASQ_OFF;
    float* mf    = ws + MF_OFF;
    float* part3 = ws + PART3_OFF;
    float* paf   = ws + PAF_OFF;
    float* y4p   = ws + Y4P_OFF;
    float* Y     = ws + Y_OFF;
    float* Mp    = ws + MP_OFF;

    kA<<<589, 256, 0, stream>>>(l3, l4, conv_w, part3, y4p, asq);
    kB<<<221, 256, 0, stream>>>(y4p, Y);
    kC<<<98, 256, 0, stream>>>(part3, Y, asq, out + MAPS_OFF);
    kD<<<221, 256, 0, stream>>>(out + MAPS_OFF, Mp);
    kE<<<3072, 256, 0, stream>>>(l3, l4, out + MAPS_OFF, Mp, out + AF_OFF, paf);
    kMF<<<384, 256, 0, stream>>>(paf, modulation, out + AF_OFF, mf);
    kF<<<(B_ * A_) / 4, 256, 0, stream>>>(mf, attr_w, attr_b, out + ATTR_OFF);
    kG<<<(B_ * NC_) / 4, 256, 0, stream>>>(out + ATTR_OFF, class_w,
                                           out + CLASS_OFF);
}

// Round 5
// 307.887 us; speedup vs baseline: 1.0319x; 1.0319x over previous
//
#include <hip/hip_runtime.h>
#include <math.h>

// Problem constants
#define B_    32
#define C3_   1024
#define C4_   2048
#define C_    3072
#define P_    784      // 28*28
#define Q_    196      // 14*14
#define L_    9
#define NG_   25088    // B_*P_
#define A_    312
#define NC_   200

// d_out layout (floats): attr(32x312), class(32x200), maps(32x9x784), af(32x3072x9)
#define ATTR_OFF  0
#define CLASS_OFF 9984
#define MAPS_OFF  16384
#define AF_OFF    242176

// workspace layout (floats)
#define ASQ_OFF   0
#define MF_OFF    16
#define PART3_OFF 98320                          // 16 slabs x 9 x NG_ = 3612672
#define PAF_OFF   98320                          // alias: part3 dead after kC1
#define Y4P_OFF   (PART3_OFF + 16 * 9 * NG_)     // 3710992 ; 32 x 32 x 9 x 196
#define LOGITS_OFF Y4P_OFF                       // alias: y4p dead after kB
#define Y_OFF     (Y4P_OFF + 32 * 32 * 9 * Q_)   // 5517328 ; 32 x 9 x 196
#define MP_OFF    (Y_OFF + 32 * 9 * Q_)          // 5573776 ; 32 x 9 x 196
// end: 5630224 floats = 22.5 MB (same footprint as round 4)

typedef __attribute__((ext_vector_type(8))) short bf16x8;
typedef __attribute__((ext_vector_type(4))) float f32x4;

__device__ __forceinline__ short f2bf(float f) {
    union { float f; unsigned u; } v; v.f = f;
    unsigned r = v.u + 0x7FFFu + ((v.u >> 16) & 1u);   // RNE
    return (short)(r >> 16);
}

// ============================================================= K_A (fused)
// blocks [0,400): l3 partials. slab = bid/25 (BLOCK-UNIFORM -> s_load weights)
// blocks [400,624): l4 contraction at 14x14. grp = (bid-400)/7 (block-uniform)
// 64 channels per slab/grp; thread owns 4 consecutive pixels (float4 loads);
// explicit 2-deep load double-buffer keeps 8 KB/wave in flight.
__global__ __launch_bounds__(256, 4) void kA(
        const float* __restrict__ l3, const float* __restrict__ l4,
        const float* __restrict__ conv_w,
        float* __restrict__ part3, float* __restrict__ y4p) {
    int bid = blockIdx.x;
    int t = threadIdx.x;

    const float* xp;
    float* outp;
    int xpitch, opitch, cbase_w;
    if (bid < 400) {
        int slab = bid / 25, rb = bid % 25;         // block-uniform slab
        int tid2 = rb * 256 + t;
        if (tid2 >= 6272) return;                   // wave-uniform exit
        int b = tid2 / 196, px = (tid2 % 196) * 4;
        xp = l3 + ((size_t)b * C3_ + slab * 64) * P_ + px;
        xpitch = P_;
        cbase_w = C4_ + slab * 64;
        outp = part3 + (size_t)(slab * 9) * NG_ + b * P_ + px;
        opitch = NG_;
    } else {
        int idx = bid - 400;
        int grp = idx / 7, rb = idx % 7;            // block-uniform grp
        int tid2 = rb * 256 + t;
        if (tid2 >= 1568) return;
        int b = tid2 / 49, q = (tid2 % 49) * 4;
        xp = l4 + ((size_t)b * C4_ + grp * 64) * Q_ + q;
        xpitch = Q_;
        cbase_w = grp * 64;
        outp = y4p + ((size_t)(b * 32 + grp) * 9) * Q_ + q;
        opitch = Q_;
    }

    float acc[9][4];
#pragma unroll
    for (int l = 0; l < 9; ++l)
#pragma unroll
        for (int j = 0; j < 4; ++j) acc[l][j] = 0.f;

    float4 v[2][8];
#pragma unroll
    for (int k = 0; k < 8; ++k)
        v[0][k] = *(const float4*)(xp + (size_t)k * xpitch);

#pragma unroll
    for (int c = 0; c < 64; c += 8) {
        int cur = (c >> 3) & 1, nxt = cur ^ 1;
        if (c < 56) {
#pragma unroll
            for (int k = 0; k < 8; ++k)
                v[nxt][k] = *(const float4*)(xp + (size_t)(c + 8 + k) * xpitch);
        }
#pragma unroll
        for (int l = 0; l < 9; ++l) {
            // block-uniform addresses -> s_load, SGPR operands in the FMAs
            const float4 w0 = *(const float4*)(conv_w + l * C_ + cbase_w + c);
            const float4 w1 = *(const float4*)(conv_w + l * C_ + cbase_w + c + 4);
            const float wv[8] = {w0.x, w0.y, w0.z, w0.w, w1.x, w1.y, w1.z, w1.w};
#pragma unroll
            for (int k = 0; k < 8; ++k) {
                acc[l][0] = fmaf(wv[k], v[cur][k].x, acc[l][0]);
                acc[l][1] = fmaf(wv[k], v[cur][k].y, acc[l][1]);
                acc[l][2] = fmaf(wv[k], v[cur][k].z, acc[l][2]);
                acc[l][3] = fmaf(wv[k], v[cur][k].w, acc[l][3]);
            }
        }
    }
#pragma unroll
    for (int l = 0; l < 9; ++l)
        *(float4*)(outp + (size_t)l * opitch) =
            make_float4(acc[l][0], acc[l][1], acc[l][2], acc[l][3]);
}

// ============================ K_B: reduce y4p -> Y[b,l,q]; block 221 does a_sq
__global__ __launch_bounds__(256) void kB(const float* __restrict__ y4p,
                                          const float* __restrict__ conv_w,
                                          float* __restrict__ Y,
                                          float* __restrict__ asq) {
    if (blockIdx.x == 221) {
        __shared__ float red[256];
        int t = threadIdx.x;
        for (int l = 0; l < L_; ++l) {
            float s = 0.f;
            for (int c = t; c < C_; c += 256) s += conv_w[l * C_ + c];
            red[t] = s; __syncthreads();
            for (int o = 128; o > 0; o >>= 1) {
                if (t < o) red[t] += red[t + o];
                __syncthreads();
            }
            if (t == 0) asq[l] = red[0];
            __syncthreads();
        }
        return;
    }
    int tid = blockIdx.x * 256 + threadIdx.x;
    if (tid >= 32 * 9 * Q_) return;
    int b = tid / (9 * Q_);
    int r = tid % (9 * Q_);
    float s = 0.f;
#pragma unroll
    for (int grp = 0; grp < 32; ++grp)
        s += y4p[(size_t)(b * 32 + grp) * (9 * Q_) + r];
    Y[(size_t)b * (9 * Q_) + r] = s;
}

// ============== K_C1: logits[l*NG_+g] = 2*(ab3+ab4_up) - asq[l]  (882 blocks)
__global__ __launch_bounds__(256) void kC1(const float* __restrict__ part3,
                                           const float* __restrict__ Y,
                                           const float* __restrict__ asq,
                                           float* __restrict__ logits) {
    int idx = blockIdx.x * 256 + threadIdx.x;   // l*NG_ + g ; exact fit
    int l = idx / NG_, g = idx % NG_;           // l is block-uniform (98 blk/l)
    int b = g / P_, p = g % P_;
    int yy = p / 28, xx = p % 28;
    float sy = 0.5f * yy - 0.25f, sx = 0.5f * xx - 0.25f;
    float fyf = floorf(sy), fxf = floorf(sx);
    float fy = sy - fyf, fx = sx - fxf;
    int ya = max(0, (int)fyf), yb = min(13, (int)fyf + 1);
    int xa = max(0, (int)fxf), xb = min(13, (int)fxf + 1);
    float w00 = (1.f - fy) * (1.f - fx), w01 = (1.f - fy) * fx;
    float w10 = fy * (1.f - fx),         w11 = fy * fx;
    const float* Yl = Y + ((size_t)b * 9 + l) * Q_;
    float ab4 = w00 * Yl[ya * 14 + xa] + w01 * Yl[ya * 14 + xb]
              + w10 * Yl[yb * 14 + xa] + w11 * Yl[yb * 14 + xb];
    float ab3 = 0.f;
#pragma unroll
    for (int sl = 0; sl < 16; ++sl)
        ab3 += part3[(size_t)(sl * 9 + l) * NG_ + g];
    logits[idx] = 2.f * (ab4 + ab3) - asq[l];
}

// ==================================== K_C2: softmax over l -> maps (98 blocks)
__global__ __launch_bounds__(256) void kC2(const float* __restrict__ logits,
                                           float* __restrict__ out_maps) {
    int g = blockIdx.x * 256 + threadIdx.x;
    int b = g / P_, p = g % P_;
    float v[9];
#pragma unroll
    for (int l = 0; l < 9; ++l) v[l] = logits[(size_t)l * NG_ + g];
    float m = v[0];
#pragma unroll
    for (int l = 1; l < 9; ++l) m = fmaxf(m, v[l]);
    float sum = 0.f;
#pragma unroll
    for (int l = 0; l < 9; ++l) { v[l] = expf(v[l] - m); sum += v[l]; }
    float inv = 1.f / sum;
#pragma unroll
    for (int l = 0; l < 9; ++l)
        out_maps[(size_t)b * (L_ * P_) + l * P_ + p] = v[l] * inv;
}

// ============== K_D: adjoint bilinear downsample of maps -> Mp[b,l,q]
__device__ __forceinline__ int adj_taps(int q, int* ys, float* wy) {
    if (q == 0)  { ys[0] = 0;  wy[0] = 1.00f; ys[1] = 1;  wy[1] = 0.75f;
                   ys[2] = 2;  wy[2] = 0.25f; return 3; }
    if (q == 13) { ys[0] = 25; wy[0] = 0.25f; ys[1] = 26; wy[1] = 0.75f;
                   ys[2] = 27; wy[2] = 1.00f; return 3; }
    ys[0] = 2 * q - 1; wy[0] = 0.25f;
    ys[1] = 2 * q;     wy[1] = 0.75f;
    ys[2] = 2 * q + 1; wy[2] = 0.75f;
    ys[3] = 2 * q + 2; wy[3] = 0.25f;
    return 4;
}

__global__ __launch_bounds__(256) void kD(const float* __restrict__ maps,
                                          float* __restrict__ Mp) {
    int tid = blockIdx.x * 256 + threadIdx.x;
    if (tid >= 32 * 9 * Q_) return;
    int b = tid / (9 * Q_);
    int r = tid % (9 * Q_);
    int l = r / Q_, q = r % Q_;
    int qy = q / 14, qx = q % 14;
    int ys[4], xs[4]; float wy[4], wx[4];
    int ny = adj_taps(qy, ys, wy);
    int nx = adj_taps(qx, xs, wx);
    const float* mrow = maps + (size_t)b * (L_ * P_) + l * P_;
    float s = 0.f;
    for (int i = 0; i < ny; ++i) {
        float rs = 0.f;
        for (int j = 0; j < nx; ++j)
            rs = fmaf(wx[j], mrow[ys[i] * 28 + xs[j]], rs);
        s = fmaf(wy[i], rs, s);
    }
    Mp[(size_t)b * (9 * Q_) + r] = s;
}

// ===================== K_E: all_features via LDS-staged MFMA bf16
// tile: 64 channels x 196 pixels; 4 waves, wave w owns channels [w*16, w*16+16)
// blocks [0,1024): l4 (b, 32 grps of 64) K=196 vs Mp -> writes out_af FINAL
// blocks [1024,3072): l3 (b, 16 grps of 64, 4 K-chunks of 196) -> partials in paf
#define SA 232     // LDS row stride (bf16 elems)
__global__ __launch_bounds__(256) void kE(
        const float* __restrict__ l3, const float* __restrict__ l4,
        const float* __restrict__ maps, const float* __restrict__ Mp,
        float* __restrict__ out_af, float* __restrict__ paf) {
    __shared__ short As[64 * SA];   // 29696 B
    __shared__ short Bs[16 * SA];   //  7424 B
    int bid = blockIdx.x;
    int t = threadIdx.x;
    int wave = t >> 6, lane = t & 63;
    int row16 = lane & 15, quad = lane >> 4;

    const float* xsrc; size_t xstride;
    const float* bsrc; size_t bstride;
    int b, c0, h;
    bool isl4 = (bid < 1024);
    if (isl4) {
        b = bid >> 5;
        c0 = (bid & 31) * 64;
        h = 0;
        xsrc = l4 + ((size_t)b * C4_ + c0) * Q_;
        xstride = Q_;
        bsrc = Mp + (size_t)b * (9 * Q_);
        bstride = Q_;
    } else {
        int idx = bid - 1024;
        b = idx >> 6;
        c0 = ((idx >> 2) & 15) * 64;
        h = idx & 3;
        xsrc = l3 + ((size_t)b * C3_ + c0) * P_ + h * Q_;
        xstride = P_;
        bsrc = maps + (size_t)b * (L_ * P_) + h * Q_;
        bstride = P_;
    }

    for (int i = t; i < 64 * 49; i += 256) {
        int r = i / 49, j = (i % 49) * 4;
        float4 v = *(const float4*)(xsrc + (size_t)r * xstride + j);
        ushort4 o;
        o.x = (unsigned short)f2bf(v.x); o.y = (unsigned short)f2bf(v.y);
        o.z = (unsigned short)f2bf(v.z); o.w = (unsigned short)f2bf(v.w);
        *(ushort4*)(As + r * SA + j) = o;
    }
    for (int i = t; i < 64 * 9; i += 256) {
        int r = i / 9, j = 196 + (i % 9) * 4;
        *(ushort4*)(As + r * SA + j) = make_ushort4(0, 0, 0, 0);
    }
    for (int i = t; i < 16 * 58; i += 256) {
        int r = i / 58, j = (i % 58) * 4;
        ushort4 o = make_ushort4(0, 0, 0, 0);
        if (r < 9 && j < 196) {
            float4 v = *(const float4*)(bsrc + (size_t)r * bstride + j);
            o.x = (unsigned short)f2bf(v.x); o.y = (unsigned short)f2bf(v.y);
            o.z = (unsigned short)f2bf(v.z); o.w = (unsigned short)f2bf(v.w);
        }
        *(ushort4*)(Bs + r * SA + j) = o;
    }
    __syncthreads();

    const short* arow = As + (wave * 16 + row16) * SA;
    const short* brow = Bs + row16 * SA;
    f32x4 acc = {0.f, 0.f, 0.f, 0.f};
#pragma unroll
    for (int k0 = 0; k0 < 224; k0 += 32) {
        bf16x8 a = *(const bf16x8*)(arow + k0 + quad * 8);
        bf16x8 bv = *(const bf16x8*)(brow + k0 + quad * 8);
        acc = __builtin_amdgcn_mfma_f32_16x16x32_bf16(a, bv, acc, 0, 0, 0);
    }
    int l = row16;
    if (l < 9) {
        int c = c0 + wave * 16 + quad * 4;
        if (isl4) {
            size_t base = ((size_t)b * C_ + c) * 9 + l;
#pragma unroll
            for (int r = 0; r < 4; ++r)
                out_af[base + (size_t)r * 9] = acc[r] * (1.f / 784.f);
        } else {
            size_t base = ((size_t)(h * B_ + b) * C3_ + c) * 9 + l;
#pragma unroll
            for (int r = 0; r < 4; ++r)
                paf[base + (size_t)r * 9] = acc[r];
        }
    }
}

// ============ K_MF: combine l3 partials -> af, and mean_features for all c
__global__ __launch_bounds__(256) void kMF(const float* __restrict__ paf,
                                           const float* __restrict__ mod,
                                           float* __restrict__ out_af,
                                           float* __restrict__ mf) {
    int i = blockIdx.x * 256 + threadIdx.x;   // b*C + c
    if (i >= B_ * C_) return;
    int b = i / C_, c = i % C_;
    float af[9];
    if (c < C4_) {
#pragma unroll
        for (int l = 0; l < 9; ++l) af[l] = out_af[(size_t)i * 9 + l];
    } else {
        int c3 = c - C4_;
#pragma unroll
        for (int l = 0; l < 9; ++l) {
            float s = 0.f;
#pragma unroll
            for (int hh = 0; hh < 4; ++hh)
                s += paf[((size_t)(hh * B_ + b) * C3_ + c3) * 9 + l];
            af[l] = s * (1.f / 784.f);
            out_af[(size_t)i * 9 + l] = af[l];
        }
    }
    const float* m = mod + (size_t)c * 9;
    float s = 0.f;
#pragma unroll
    for (int l = 0; l < 8; ++l) s = fmaf(af[l], m[l], s);
    mf[i] = s * 0.125f;
}

// -------------------------------------------------- K_F: attr = mf @ attr_w.T
__global__ __launch_bounds__(256) void kF(
        const float* __restrict__ mf, const float* __restrict__ attr_w,
        const float* __restrict__ attr_b, float* __restrict__ out_attr) {
    int idx = blockIdx.x * 4 + (threadIdx.x >> 6);   // idx = b*312 + a
    int lane = threadIdx.x & 63;
    int b = idx / A_, a = idx % A_;
    const float4* wr = (const float4*)(attr_w + (size_t)a * C_);
    const float4* mr = (const float4*)(mf + (size_t)b * C_);
    float acc = 0.f;
    for (int j = lane; j < C_ / 4; j += 64) {
        float4 w = wr[j], m = mr[j];
        acc += w.x * m.x + w.y * m.y + w.z * m.z + w.w * m.w;
    }
    acc += __shfl_xor(acc, 1);  acc += __shfl_xor(acc, 2);
    acc += __shfl_xor(acc, 4);  acc += __shfl_xor(acc, 8);
    acc += __shfl_xor(acc, 16); acc += __shfl_xor(acc, 32);
    if (lane == 0) out_attr[idx] = acc + attr_b[a];
}

// ---------------------------------------------- K_G: class = attr @ class_w.T
__global__ __launch_bounds__(256) void kG(
        const float* __restrict__ attr, const float* __restrict__ class_w,
        float* __restrict__ out_class) {
    int idx = blockIdx.x * 4 + (threadIdx.x >> 6);   // idx = b*200 + n
    int lane = threadIdx.x & 63;
    int b = idx / NC_, n = idx % NC_;
    float acc = 0.f;
    for (int a = lane; a < A_; a += 64)
        acc += attr[b * A_ + a] * class_w[n * A_ + a];
    acc += __shfl_xor(acc, 1);  acc += __shfl_xor(acc, 2);
    acc += __shfl_xor(acc, 4);  acc += __shfl_xor(acc, 8);
    acc += __shfl_xor(acc, 16); acc += __shfl_xor(acc, 32);
    if (lane == 0) out_class[idx] = acc;
}

extern "C" void kernel_launch(void* const* d_in, const int* in_sizes, int n_in,
                              void* d_out, int out_size, void* d_ws, size_t ws_size,
                              hipStream_t stream) {
    (void)in_sizes; (void)n_in; (void)out_size; (void)ws_size;
    const float* l3         = (const float*)d_in[0];
    const float* l4         = (const float*)d_in[1];
    const float* conv_w     = (const float*)d_in[2];
    const float* modulation = (const float*)d_in[3];
    const float* attr_w     = (const float*)d_in[4];
    const float* attr_b     = (const float*)d_in[5];
    const float* class_w    = (const float*)d_in[6];
    float* out = (float*)d_out;
    float* ws  = (float*)d_ws;
    float* asq    = ws + ASQ_OFF;
    float* mf     = ws + MF_OFF;
    float* part3  = ws + PART3_OFF;
    float* paf    = ws + PAF_OFF;
    float* y4p    = ws + Y4P_OFF;
    float* logits = ws + LOGITS_OFF;
    float* Y      = ws + Y_OFF;
    float* Mp     = ws + MP_OFF;

    kA<<<624, 256, 0, stream>>>(l3, l4, conv_w, part3, y4p);
    kB<<<222, 256, 0, stream>>>(y4p, conv_w, Y, asq);
    kC1<<<882, 256, 0, stream>>>(part3, Y, asq, logits);
    kC2<<<98, 256, 0, stream>>>(logits, out + MAPS_OFF);
    kD<<<221, 256, 0, stream>>>(out + MAPS_OFF, Mp);
    kE<<<3072, 256, 0, stream>>>(l3, l4, out + MAPS_OFF, Mp, out + AF_OFF, paf);
    kMF<<<384, 256, 0, stream>>>(paf, modulation, out + AF_OFF, mf);
    kF<<<(B_ * A_) / 4, 256, 0, stream>>>(mf, attr_w, attr_b, out + ATTR_OFF);
    kG<<<(B_ * NC_) / 4, 256, 0, stream>>>(out + ATTR_OFF, class_w,
                                           out + CLASS_OFF);
}